// Round 1
// baseline (518.516 us; speedup 1.0000x reference)
//
#include <hip/hip_runtime.h>

#define NBINS 4096
#define BPT (NBINS / 256)   // bins per thread in scan kernel

struct SelState {
  unsigned prefix;
  unsigned krem;
  unsigned bins[NBINS];
};

// Zero histogram, set selection state. d_ws is poisoned 0xAA before every call.
__global__ __launch_bounds__(256) void init_state_kernel(SelState* st, unsigned k) {
  int t = threadIdx.x;
  for (int j = t; j < NBINS; j += 256) st->bins[j] = 0u;
  if (t == 0) { st->prefix = 0u; st->krem = k; }
}

// Streaming SiLU: r = x / (1 + exp(-x)), float4 vectorized, grid-stride.
__global__ __launch_bounds__(256) void silu_kernel(const float4* __restrict__ x,
                                                   float4* __restrict__ out, int nvec) {
  int i = blockIdx.x * blockDim.x + threadIdx.x;
  int stride = gridDim.x * blockDim.x;
  for (; i < nvec; i += stride) {
    float4 v = x[i];
    float4 r;
    r.x = v.x / (1.0f + __expf(-v.x));
    r.y = v.y / (1.0f + __expf(-v.y));
    r.z = v.z / (1.0f + __expf(-v.z));
    r.w = v.w / (1.0f + __expf(-v.w));
    out[i] = r;
  }
}

// One radix-select histogram pass over |x[0]| bit patterns.
// Candidates: (abs_bits & mask) == prefix. Bin: (abs_bits >> shift) & (NBINS-1).
__global__ __launch_bounds__(256) void hist_kernel(const uint4* __restrict__ x, int nvec,
                                                   SelState* __restrict__ st,
                                                   unsigned shift, unsigned mask) {
  __shared__ unsigned lbins[NBINS];
  for (int j = threadIdx.x; j < NBINS; j += 256) lbins[j] = 0u;
  __syncthreads();
  unsigned prefix = st->prefix;  // wave-uniform scalar load (updated by prior scan kernel)
  int i = blockIdx.x * blockDim.x + threadIdx.x;
  int stride = gridDim.x * blockDim.x;
  for (; i < nvec; i += stride) {
    uint4 v = x[i];
    unsigned a;
    a = v.x & 0x7fffffffu; if ((a & mask) == prefix) atomicAdd(&lbins[(a >> shift) & (NBINS - 1)], 1u);
    a = v.y & 0x7fffffffu; if ((a & mask) == prefix) atomicAdd(&lbins[(a >> shift) & (NBINS - 1)], 1u);
    a = v.z & 0x7fffffffu; if ((a & mask) == prefix) atomicAdd(&lbins[(a >> shift) & (NBINS - 1)], 1u);
    a = v.w & 0x7fffffffu; if ((a & mask) == prefix) atomicAdd(&lbins[(a >> shift) & (NBINS - 1)], 1u);
  }
  __syncthreads();
  for (int j = threadIdx.x; j < NBINS; j += 256) {
    unsigned c = lbins[j];
    if (c) atomicAdd(&st->bins[j], c);
  }
}

// Single-block scan: find the bin containing rank krem, update prefix/krem, zero bins.
// On the final pass, write outliner + scale to out_scalars.
__global__ __launch_bounds__(256) void scan_kernel(SelState* __restrict__ st, unsigned shift,
                                                   float* __restrict__ out_scalars) {
  __shared__ unsigned csum[256];
  const int t = threadIdx.x;
  unsigned local[BPT];
  unsigned s = 0;
  for (int j = 0; j < BPT; ++j) {
    local[j] = st->bins[t * BPT + j];
    s += local[j];
  }
  csum[t] = s;
  __syncthreads();
  // Hillis-Steele inclusive scan over the 256 per-thread chunk sums
  for (int off = 1; off < 256; off <<= 1) {
    unsigned add = (t >= off) ? csum[t - off] : 0u;
    __syncthreads();
    csum[t] += add;
    __syncthreads();
  }
  unsigned incl = csum[t];
  unsigned excl = incl - s;
  unsigned krem = st->krem;
  if (krem > excl && krem <= incl) {   // exactly one thread takes this
    unsigned run = excl;
    unsigned newprefix = st->prefix;
    for (int j = 0; j < BPT; ++j) {
      if (krem <= run + local[j]) {
        unsigned b = (unsigned)(t * BPT + j);
        newprefix |= (b << shift);
        st->prefix = newprefix;
        st->krem = krem - run;
        if (out_scalars) {
          float v = __uint_as_float(newprefix);
          out_scalars[0] = v;            // outliner
          out_scalars[1] = v / 127.0f;   // scale = max(|x_sub0|)/qmax == outliner/127
        }
        break;
      }
      run += local[j];
    }
  }
  __syncthreads();
  for (int j = 0; j < BPT; ++j) st->bins[t * BPT + j] = 0u;  // ready for next pass
}

extern "C" void kernel_launch(void* const* d_in, const int* in_sizes, int n_in,
                              void* d_out, int out_size, void* d_ws, size_t ws_size,
                              hipStream_t stream) {
  const float* x = (const float*)d_in[0];
  float* out = (float*)d_out;
  const int n = in_sizes[0];     // 8*2048*4096 = 67108864
  const int n0 = n / 8;          // one batch element = 8388608
  // k = int(n0 * (1 - 0.01)), python int() truncation semantics
  const unsigned k = (unsigned)((double)n0 * 0.99);

  SelState* st = (SelState*)d_ws;

  init_state_kernel<<<1, 256, 0, stream>>>(st, k);

  const int nvec0 = n0 / 4;
  dim3 hb(256), hg(2048);
  // 31 significant bits (abs mask clears bit 31): passes cover bits [30:19], [18:7], [6:0]
  hist_kernel<<<hg, hb, 0, stream>>>((const uint4*)x, nvec0, st, 19u, 0x00000000u);
  scan_kernel<<<1, 256, 0, stream>>>(st, 19u, nullptr);
  hist_kernel<<<hg, hb, 0, stream>>>((const uint4*)x, nvec0, st, 7u, 0xFFF80000u);
  scan_kernel<<<1, 256, 0, stream>>>(st, 7u, nullptr);
  hist_kernel<<<hg, hb, 0, stream>>>((const uint4*)x, nvec0, st, 0u, 0xFFFFFF80u);
  scan_kernel<<<1, 256, 0, stream>>>(st, 0u, out + n);

  const int nvec = n / 4;
  silu_kernel<<<4096, 256, 0, stream>>>((const float4*)x, (float4*)out, nvec);
}